// Round 14
// baseline (1386.869 us; speedup 1.0000x reference)
//
#include <hip/hip_runtime.h>
#include <math.h>

#define S_LEN 256
#define NCELL 8
#define HID 16
#define MEM 20
#define NB 4
#define NTHR 512
#define RSTR 2592   // ring batch stride in f16 (bank skew)

typedef _Float16 v8h __attribute__((ext_vector_type(8)));
typedef float v4f __attribute__((ext_vector_type(4)));

__device__ __forceinline__ float sigm(float v) { return 1.0f / (1.0f + __expf(-v)); }
__device__ __forceinline__ float tanh_f(float v) { return 1.0f - 2.0f / (__expf(2.0f * v) + 1.0f); }
__device__ __forceinline__ float dot4(float4 a, float4 b) {
    return fmaf(a.x, b.x, fmaf(a.y, b.y, fmaf(a.z, b.z, a.w * b.w)));
}
__device__ __forceinline__ v4f mfma16(v8h a, v8h b, v4f c) {
    return __builtin_amdgcn_mfma_f32_16x16x32_f16(a, b, c, 0, 0, 0);
}

#define RING(b, s, k) ringH[(b) * RSTR + (s) * 128 + (k)]

// prep: W1F (163840 f16, MFMA A-frag order, verified R11) + WAF (16384 f16)
__global__ __launch_bounds__(256)
void prep_w(const float* __restrict__ W1, const float* __restrict__ W_hh,
            const float* __restrict__ W_ih, const float* __restrict__ b_ih,
            const float* __restrict__ b_hh, _Float16* __restrict__ W1F,
            _Float16* __restrict__ WAF) {
    int idx = blockIdx.x * 256 + threadIdx.x;
    if (idx < 163840) {
        int e = idx & 7, lane = (idx >> 3) & 63, jt = (idx >> 9) & 3, t = idx >> 11;
        int m = t >> 2, kc = t & 3;
        int j = jt * 16 + (lane & 15);
        int k = kc * 32 + (lane >> 4) * 8 + e;
        W1F[idx] = (_Float16)W1[j * 2580 + m * 129 + k];
    } else if (idx < 163840 + 16384) {
        int d = idx - 163840;
        int e = d & 7, lane = (d >> 3) & 63, gate = (d >> 9) & 3, c = d >> 11;
        int m = lane & 15, k = (lane >> 4) * 8 + e;
        int row = c * 64 + gate * 16 + m;
        float v = 0.f;
        if (k < 16) v = W_hh[row * 16 + k];
        else if (k == 16) v = W_ih[row];
        else if (k == 17) v = b_ih[row] + b_hh[row];
        WAF[d] = (_Float16)v;
    }
}

// R13 elimination: spill/conflicts/tail/phase-A-LDS all non-binding. Remaining
// candidate: stream global-load volume (308 KB/CU/step). R14: 2-step temporal
// blocking -- on even steps one pass over W1 m=1..19 accumulates BOTH
// partial(t+1) [m>=1] and partial(t+2) [m>=2] (same A-tiles, 2 B-rows, 8
// accs). Odd steps: only the missing m=1 term for t+2 (W1_1 LDS-cached, 4
// tiles in 2a). Stream bytes/step halve; MFMA count unchanged.
#define E1P_ODD(BB, V) { \
    V = b1_l[lane] \
      + redP[1][BB][lane] + redP[2][BB][lane] + redP[3][BB][lane] \
      + redP[4][BB][lane] + redP[5][BB][lane] + redP[6][BB][lane] + redP[7][BB][lane]; }

#define E1P_EVEN(BB, V) { \
    V = b1_l[lane] \
      + redQ[1][BB][lane] + redQ[2][BB][lane] + redQ[3][BB][lane] \
      + redQ[4][BB][lane] + redQ[5][BB][lane] + redQ[6][BB][lane] + redQ[7][BB][lane] \
      + redD[0][BB][lane] + redD[1][BB][lane] + redD[2][BB][lane] + redD[3][BB][lane]; }

#define E1F(BB, V) { \
    V += errdotS[BB][lane] \
       + red0[0][BB][lane] + red0[1][BB][lane] + red0[2][BB][lane] + red0[3][BB][lane]; \
    e1S[BB][lane] = fmaxf(V, 0.f); }

__global__ __attribute__((amdgpu_flat_work_group_size(NTHR, NTHR)))
void mmoe_kernel(const float* __restrict__ x, const float* __restrict__ pred0,
                 const float* __restrict__ gate0,
                 const float* __restrict__ W_ih, const float* __restrict__ W_hh,
                 const float* __restrict__ b_ih, const float* __restrict__ b_hh,
                 const float* __restrict__ W_o, const float* __restrict__ b_o,
                 const float* __restrict__ W1, const float* __restrict__ b1,
                 const float* __restrict__ W2, const float* __restrict__ b2,
                 const float* __restrict__ Wg, const float* __restrict__ bg,
                 const float* __restrict__ Wa_ih, const float* __restrict__ Wa_hh,
                 const float* __restrict__ ba_ih, const float* __restrict__ ba_hh,
                 const _Float16* __restrict__ W1F, const _Float16* __restrict__ WAF,
                 float* __restrict__ out)
{
    __shared__ __align__(16) _Float16 ringH[NB * RSTR];      // skewed ring (h rows)
    __shared__ __align__(16) _Float16 W10F_l[8192];          // m=0 A-frags (16 KB)
    __shared__ __align__(16) _Float16 W11F_l[8192];          // m=1 A-frags (16 KB)
    __shared__ __align__(16) _Float16 ehH[NB][40];           // [eh(16)|x|1|0..] f16
    __shared__ float errS[NB][MEM];
    __shared__ __align__(16) float WaI[2][64 * 20], WaH[2][64 * 20];
    __shared__ float ba_l[2][64];
    __shared__ __align__(16) float W2_l[16 * 68];
    __shared__ float b2_l[16];
    __shared__ __align__(16) float Wg_l[8][16], Wo_l[8][16];
    __shared__ float bg_l[8], bo_l[8];
    __shared__ float Werr_l[MEM * 64];
    __shared__ float b1_l[64];
    __shared__ float xS[NB][S_LEN];
    __shared__ __align__(16) float ecS[NB][HID];
    __shared__ __align__(16) float nhS[NB][NCELL][HID], ncS[NB][NCELL][HID];
    __shared__ float oS[NB][NCELL], predS[NB], gateS[NB][NCELL];
    __shared__ __align__(16) float ahS[2][NB][HID], acS[2][NB][HID];
    __shared__ __align__(16) float e1S[NB][64], aiS[NB][HID];
    __shared__ __align__(16) float glog[NB][8];
    __shared__ __align__(16) float redP[8][NB][64];          // partial(t+1), even 2b
    __shared__ __align__(16) float redQ[8][NB][64];          // partial(t+2) m>=2, even 2b
    __shared__ __align__(16) float redD[4][NB][64];          // m=1 fixup, odd 2a
    __shared__ __align__(16) float red0[4][NB][64];          // m=0 term, every 2a
    __shared__ float errdotS[NB][64];
    __shared__ float thS[NB];

    const int tid = threadIdx.x;
    const int b0 = blockIdx.x * NB;
    const int lane = tid & 63, wv = tid >> 6;
    const int quad = lane >> 4, nn = lane & 15, bb4 = nn & 3;

    // ---- one-time staging ----
    for (int i = tid; i < 2048; i += NTHR) {
        int l = i >> 10, r = i & 1023, g = r >> 4, q = r & 15;
        WaI[l][g * 20 + q] = Wa_ih[i]; WaH[l][g * 20 + q] = Wa_hh[i];
    }
    for (int i = tid; i < 128; i += NTHR) { int l = i >> 6, g = i & 63; ba_l[l][g] = ba_ih[i] + ba_hh[i]; }
    for (int i = tid; i < 1024; i += NTHR) { int r = i >> 6, q = i & 63; W2_l[r * 68 + q] = W2[i]; }
    for (int i = tid; i < 1280; i += NTHR) { int m = i >> 6, j = i & 63; Werr_l[i] = W1[j * 2580 + m * 129 + 128]; }
    for (int i = tid; i < 8192; i += NTHR) { W10F_l[i] = W1F[i]; W11F_l[i] = W1F[8192 + i]; }
    if (tid < 64) b1_l[tid] = b1[tid];
    if (tid < 16) b2_l[tid] = b2[tid];
    if (tid < 128) { int c = tid >> 4, h = tid & 15; Wg_l[c][h] = Wg[tid]; Wo_l[c][h] = W_o[tid]; }
    if (tid < 8) { bg_l[tid] = bg[tid]; bo_l[tid] = b_o[tid]; }
    for (int i = tid; i < NB * S_LEN; i += NTHR) { int b = i >> 8, s = i & 255; xS[b][s] = x[(b0 + b) * S_LEN + s]; }
    for (int i = tid; i < NB * RSTR; i += NTHR) ringH[i] = (_Float16)0.0f;
    for (int i = tid; i < 8 * NB * 64; i += NTHR) { ((float*)redP)[i] = 0.0f; ((float*)redQ)[i] = 0.0f; }
    for (int i = tid; i < 4 * NB * 64; i += NTHR) ((float*)redD)[i] = 0.0f;
    if (tid < NB * 40) {
        int n = tid / 40, k = tid % 40;
        float v = 0.f;
        if (k == 16) v = x[(b0 + n) * S_LEN + 0];
        else if (k == 17) v = 1.0f;
        ehH[n][k] = (_Float16)v;
    }
    if (tid < NB * MEM) { int b = tid / MEM, m = tid % MEM; errS[b][m] = 0.5f; }
    if (tid < NB * HID) {
        int b = tid >> 4, h = tid & 15;
        ecS[b][h] = 0.f;
        ahS[0][b][h] = 0.f; ahS[1][b][h] = 0.f;
        acS[0][b][h] = 0.f; acS[1][b][h] = 0.f;
    }
    if (tid < NB) predS[tid] = pred0[b0 + tid];
    if (tid < NB * NCELL) { int b = tid >> 3, c = tid & 7; gateS[b][c] = gate0[(b0 + b) * NCELL + c]; }

    // ---- loop-invariant expert A-frags (cell = wv) ----
    const v8h* WA = (const v8h*)WAF;
    v8h aI = WA[(wv * 4 + 0) * 64 + lane];
    v8h aF = WA[(wv * 4 + 1) * 64 + lane];
    v8h aG = WA[(wv * 4 + 2) * 64 + lane];
    v8h aO = WA[(wv * 4 + 3) * 64 + lane];
    __syncthreads();

    const v8h* Wb = (const v8h*)W1F;
    const v8h* WL0 = (const v8h*)W10F_l;
    const v8h* WL1 = (const v8h*)W11F_l;

    int head = 0;
    #pragma unroll 1
    for (int t = 0; t < S_LEN; ++t) {
        head = (head == 0) ? (MEM - 1) : (head - 1);
        const int par = t & 1;                               // 0 = even (stream step)
        float v0, v1, v2, v3;

        // ---- Section 1: phase A via MFMA (wave = cell wv) ----
        {
            v8h bfrag = *(const v8h*)&ehH[bb4][quad * 8];
            v4f z4 = {0.f, 0.f, 0.f, 0.f};
            v4f zi = mfma16(aI, bfrag, z4);
            v4f zf = mfma16(aF, bfrag, z4);
            v4f zg = mfma16(aG, bfrag, z4);
            v4f zo = mfma16(aO, bfrag, z4);
            if (nn < 4) {
                int b = nn, c = wv;
                #pragma unroll
                for (int r = 0; r < 4; ++r) {
                    int h = quad * 4 + r;
                    float cc = ecS[b][h];
                    float c2 = sigm(zf[r]) * cc + sigm(zi[r]) * tanh_f(zg[r]);
                    float hv = sigm(zo[r]) * tanh_f(c2);
                    nhS[b][c][h] = hv; ncS[b][c][h] = c2;
                    RING(b, head, c * 16 + h) = (_Float16)hv;
                }
            }
            if (tid < NB) errS[tid][head] = xS[tid][t] - predS[tid];
        }
        __syncthreads();   // B1

        // ---- Section 2a: m=0 MFMA (+ odd: m=1 fixup) + parallel tail-prep ----
        {
            int kc = wv >> 1, jt0 = (wv & 1) * 2;
            v8h bfrag = *(const v8h*)&RING(bb4, head, kc * 32 + quad * 8);
            v8h a0 = WL0[(kc * 4 + jt0) * 64 + lane];
            v8h a1 = WL0[(kc * 4 + jt0 + 1) * 64 + lane];
            v4f z = {0.f, 0.f, 0.f, 0.f};
            v4f c0 = mfma16(a0, bfrag, z);
            v4f c1 = mfma16(a1, bfrag, z);
            if (nn < 4) {
                *(v4f*)&red0[kc][nn][jt0 * 16 + quad * 4] = c0;
                *(v4f*)&red0[kc][nn][(jt0 + 1) * 16 + quad * 4] = c1;
            }
            if (par == 1) {   // odd: Delta = W1_1 . row(t)  (m=1 term for step t+1)
                v8h d0 = WL1[(kc * 4 + jt0) * 64 + lane];
                v8h d1 = WL1[(kc * 4 + jt0 + 1) * 64 + lane];
                v4f e0 = mfma16(d0, bfrag, z);
                v4f e1 = mfma16(d1, bfrag, z);
                if (nn < 4) {
                    *(v4f*)&redD[kc][nn][jt0 * 16 + quad * 4] = e0;
                    *(v4f*)&redD[kc][nn][(jt0 + 1) * 16 + quad * 4] = e1;
                }
            }
            if (wv == 0) {
                if (par == 0) { E1P_EVEN(0, v0) E1P_EVEN(1, v1) E1P_EVEN(2, v2) E1P_EVEN(3, v3) }
                else         { E1P_ODD(0, v0)  E1P_ODD(1, v1)  E1P_ODD(2, v2)  E1P_ODD(3, v3) }
            } else if (wv == 1) {
                if (lane < 32) {
                    int bb = lane >> 3, c = lane & 7;
                    const float4* np_ = (const float4*)&nhS[bb][c][0];
                    const float4* wp = (const float4*)&Wo_l[c][0];
                    float s = bo_l[c];
                    #pragma unroll
                    for (int q4 = 0; q4 < 4; ++q4) s += dot4(np_[q4], wp[q4]);
                    oS[bb][c] = s;
                }
            } else if (wv == 2) {
                if (lane < NB) {
                    float th = 0.f;
                    #pragma unroll
                    for (int m = 0; m < 10; ++m) {
                        int sl = head + m; if (sl >= MEM) sl -= MEM;
                        th += fabsf(errS[lane][sl]);
                    }
                    th *= 0.25f;
                    thS[lane] = fminf(fmaxf(th, 0.f), 1.f);
                }
            } else if (wv >= 3 && wv < 7) {
                int bb = wv - 3;
                float s = 0.f;
                int sl = head;
                #pragma unroll
                for (int m = 0; m < MEM; ++m) {
                    s = fmaf(Werr_l[m * 64 + lane], errS[bb][sl], s);
                    ++sl; if (sl >= MEM) sl = 0;
                }
                errdotS[bb][lane] = s;
            }
        }
        __syncthreads();   // B2

        // ---- Section 2b: even = double-stream (waves 1-7) || tail (wave 0) ----
        if (wv == 0) {
            // ---- tail (every step) ----
            E1F(0, v0) E1F(1, v1) E1F(2, v2) E1F(3, v3)
            const int j = lane;
            {   // ai: 64 lanes = 4b x 16i
                int bb = j >> 4, i = j & 15;
                const float4* epq = (const float4*)&e1S[bb][0];
                float s = b2_l[i];
                #pragma unroll
                for (int q = 0; q < 16; ++q) s += dot4(*(const float4*)&W2_l[i * 68 + q * 4], epq[q]);
                aiS[bb][i] = fmaxf(s, 0.f);
            }
            #pragma unroll
            for (int l = 0; l < 2; ++l) {   // agent LSTM
                int bb = j >> 4, h = j & 15;
                const float4* ip = (l == 0) ? (const float4*)&aiS[bb][0]
                                            : (const float4*)&ahS[0][bb][0];
                const float4* hp = (const float4*)&ahS[l][bb][0];
                float4 i0 = ip[0], i1 = ip[1], i2 = ip[2], i3 = ip[3];
                float4 h0 = hp[0], h1 = hp[1], h2v = hp[2], h3 = hp[3];
                float zg[4];
                #pragma unroll
                for (int gi = 0; gi < 4; ++gi) {
                    int g = gi * 16 + h;
                    const float* wi = &WaI[l][g * 20];
                    const float* wh = &WaH[l][g * 20];
                    float z = ba_l[l][g];
                    z += dot4(i0, *(const float4*)&wi[0]) + dot4(i1, *(const float4*)&wi[4])
                       + dot4(i2, *(const float4*)&wi[8]) + dot4(i3, *(const float4*)&wi[12]);
                    z += dot4(h0, *(const float4*)&wh[0]) + dot4(h1, *(const float4*)&wh[4])
                       + dot4(h2v, *(const float4*)&wh[8]) + dot4(h3, *(const float4*)&wh[12]);
                    zg[gi] = z;
                }
                float c2 = sigm(zg[1]) * acS[l][bb][h] + sigm(zg[0]) * tanh_f(zg[2]);
                acS[l][bb][h] = c2;
                ahS[l][bb][h] = sigm(zg[3]) * tanh_f(c2);
            }
            if (j < 32) {   // gate logits + softmax + theta blend
                int bb = j >> 3, c = j & 7;
                const float4* hp = (const float4*)&ahS[1][bb][0];
                const float4* wg = (const float4*)&Wg_l[c][0];
                float s = bg_l[c];
                #pragma unroll
                for (int q = 0; q < 4; ++q) s += dot4(wg[q], hp[q]);
                glog[bb][c] = s;
                float4 ga = *(const float4*)&glog[bb][0];
                float4 gb = *(const float4*)&glog[bb][4];
                float mx = fmaxf(fmaxf(fmaxf(ga.x, ga.y), fmaxf(ga.z, ga.w)),
                                 fmaxf(fmaxf(gb.x, gb.y), fmaxf(gb.z, gb.w)));
                float sum = __expf(ga.x - mx) + __expf(ga.y - mx) + __expf(ga.z - mx) + __expf(ga.w - mx)
                          + __expf(gb.x - mx) + __expf(gb.y - mx) + __expf(gb.z - mx) + __expf(gb.w - mx);
                float p = __expf(s - mx) / sum;
                float th = thS[bb];
                gateS[bb][c] = p * th + gateS[bb][c] * (1.f - th);
            }
            {   // combine -> ehH + ecS
                int bb = j >> 4, h = j & 15;
                float se = 0.f, sc = 0.f;
                #pragma unroll
                for (int c = 0; c < 8; ++c) {
                    float g = gateS[bb][c];
                    se = fmaf(g, nhS[bb][c][h], se);
                    sc = fmaf(g, ncS[bb][c][h], sc);
                }
                ehH[bb][h] = (_Float16)se;
                ecS[bb][h] = sc;
            }
            if (j < NB) {   // pred + output + next x slot
                float s = 0.f;
                #pragma unroll
                for (int c = 0; c < 8; ++c) s = fmaf(gateS[j][c], oS[j][c], s);
                predS[j] = s;
                out[(b0 + j) * S_LEN + t] = s;
                ehH[j][16] = (_Float16)((t + 1 < S_LEN) ? xS[j][t + 1] : 0.f);
            }
        } else if (par == 0) {
            // ---- even double-stream: P1 (m=1..19 for t+1) + P2 (m=2..19 for t+2) ----
            int kt = (wv - 1) * 11;
            int ktEnd = kt + 11; if (ktEnd > 76) ktEnd = 76;
            v4f c0 = {0.f,0.f,0.f,0.f}, c1 = {0.f,0.f,0.f,0.f};
            v4f c2 = {0.f,0.f,0.f,0.f}, c3 = {0.f,0.f,0.f,0.f};
            v4f d0 = {0.f,0.f,0.f,0.f}, d1 = {0.f,0.f,0.f,0.f};
            v4f d2 = {0.f,0.f,0.f,0.f}, d3 = {0.f,0.f,0.f,0.f};
            size_t tb = (size_t)(4 + kt) * 256 + lane;
            v8h pA0 = Wb[tb], pA1 = Wb[tb + 64], pA2 = Wb[tb + 128], pA3 = Wb[tb + 192];
            #pragma unroll 1
            for (; kt < ktEnd; ++kt) {
                v8h A0 = pA0, A1 = pA1, A2 = pA2, A3 = pA3;
                int kn = kt + 1;
                if (kn < ktEnd) {
                    size_t tn = (size_t)(4 + kn) * 256 + lane;
                    pA0 = Wb[tn]; pA1 = Wb[tn + 64]; pA2 = Wb[tn + 128]; pA3 = Wb[tn + 192];
                }
                int m = 1 + (kt >> 2), kc = kt & 3;
                int sp = head + m - 1; if (sp >= MEM) sp -= MEM;
                v8h BP = *(const v8h*)&RING(bb4, sp, kc * 32 + quad * 8);
                c0 = mfma16(A0, BP, c0);
                c1 = mfma16(A1, BP, c1);
                c2 = mfma16(A2, BP, c2);
                c3 = mfma16(A3, BP, c3);
                if (m >= 2) {
                    int sq = sp - 1; if (sq < 0) sq += MEM;
                    v8h BQ = *(const v8h*)&RING(bb4, sq, kc * 32 + quad * 8);
                    d0 = mfma16(A0, BQ, d0);
                    d1 = mfma16(A1, BQ, d1);
                    d2 = mfma16(A2, BQ, d2);
                    d3 = mfma16(A3, BQ, d3);
                }
            }
            if (nn < 4) {
                *(v4f*)&redP[wv][nn][ 0 + quad * 4] = c0;
                *(v4f*)&redP[wv][nn][16 + quad * 4] = c1;
                *(v4f*)&redP[wv][nn][32 + quad * 4] = c2;
                *(v4f*)&redP[wv][nn][48 + quad * 4] = c3;
                *(v4f*)&redQ[wv][nn][ 0 + quad * 4] = d0;
                *(v4f*)&redQ[wv][nn][16 + quad * 4] = d1;
                *(v4f*)&redQ[wv][nn][32 + quad * 4] = d2;
                *(v4f*)&redQ[wv][nn][48 + quad * 4] = d3;
            }
        }
        __syncthreads();   // B3
    }
}

extern "C" void kernel_launch(void* const* d_in, const int* in_sizes, int n_in,
                              void* d_out, int out_size, void* d_ws, size_t ws_size,
                              hipStream_t stream) {
    const float* xp    = (const float*)d_in[0];
    const float* pred0 = (const float*)d_in[1];
    const float* gate0 = (const float*)d_in[2];
    const float* W_ih  = (const float*)d_in[3];
    const float* W_hh  = (const float*)d_in[4];
    const float* b_ih  = (const float*)d_in[5];
    const float* b_hh  = (const float*)d_in[6];
    const float* W_o   = (const float*)d_in[7];
    const float* b_o   = (const float*)d_in[8];
    const float* W1    = (const float*)d_in[9];
    const float* b1    = (const float*)d_in[10];
    const float* W2    = (const float*)d_in[11];
    const float* b2    = (const float*)d_in[12];
    const float* Wg    = (const float*)d_in[13];
    const float* bg    = (const float*)d_in[14];
    const float* Wa_ih = (const float*)d_in[15];
    const float* Wa_hh = (const float*)d_in[16];
    const float* ba_ih = (const float*)d_in[17];
    const float* ba_hh = (const float*)d_in[18];
    _Float16* W1F = (_Float16*)d_ws;                 // 320 KB
    _Float16* WAF = W1F + 163840;                    // +32 KB expert A-frags

    prep_w<<<(163840 + 16384 + 255) / 256, 256, 0, stream>>>(
        W1, W_hh, W_ih, b_ih, b_hh, W1F, WAF);
    mmoe_kernel<<<512 / NB, NTHR, 0, stream>>>(
        xp, pred0, gate0, W_ih, W_hh, b_ih, b_hh, W_o, b_o,
        W1, b1, W2, b2, Wg, bg, Wa_ih, Wa_hh, ba_ih, ba_hh,
        W1F, WAF, (float*)d_out);
}

// Round 15
// 1281.536 us; speedup vs baseline: 1.0822x; 1.0822x over previous
//
#include <hip/hip_runtime.h>
#include <math.h>

#define S_LEN 256
#define NCELL 8
#define HID 16
#define MEM 20
#define NB 4
#define NTHR 512
#define RSTR 2592   // ring batch stride in f16 (bank skew)
#define RP 80       // reduction row stride (floats): bank shift 16 -> 2-way

typedef _Float16 v8h __attribute__((ext_vector_type(8)));
typedef _Float16 v4h __attribute__((ext_vector_type(4)));
typedef float v4f __attribute__((ext_vector_type(4)));

__device__ __forceinline__ float sigm(float v) { return 1.0f / (1.0f + __expf(-v)); }
__device__ __forceinline__ float tanh_f(float v) { return 1.0f - 2.0f / (__expf(2.0f * v) + 1.0f); }
__device__ __forceinline__ float dot4(float4 a, float4 b) {
    return fmaf(a.x, b.x, fmaf(a.y, b.y, fmaf(a.z, b.z, a.w * b.w)));
}
__device__ __forceinline__ v4f mfma16(v8h a, v8h b, v4f c) {
    return __builtin_amdgcn_mfma_f32_16x16x32_f16(a, b, c, 0, 0, 0);
}

#define RING(b, s, k) ringH[(b) * RSTR + (s) * 128 + (k)]

// prep: W1F (163840 f16, MFMA A-frag order, verified R11) + WAF (16384 f16)
__global__ __launch_bounds__(256)
void prep_w(const float* __restrict__ W1, const float* __restrict__ W_hh,
            const float* __restrict__ W_ih, const float* __restrict__ b_ih,
            const float* __restrict__ b_hh, _Float16* __restrict__ W1F,
            _Float16* __restrict__ WAF) {
    int idx = blockIdx.x * 256 + threadIdx.x;
    if (idx < 163840) {
        int e = idx & 7, lane = (idx >> 3) & 63, jt = (idx >> 9) & 3, t = idx >> 11;
        int m = t >> 2, kc = t & 3;
        int j = jt * 16 + (lane & 15);
        int k = kc * 32 + (lane >> 4) * 8 + e;
        W1F[idx] = (_Float16)W1[j * 2580 + m * 129 + k];
    } else if (idx < 163840 + 16384) {
        int d = idx - 163840;
        int e = d & 7, lane = (d >> 3) & 63, gate = (d >> 9) & 3, c = d >> 11;
        int m = lane & 15, k = (lane >> 4) * 8 + e;
        int row = c * 64 + gate * 16 + m;
        float v = 0.f;
        if (k < 16) v = W_hh[row * 16 + k];
        else if (k == 16) v = W_ih[row];
        else if (k == 17) v = b_ih[row] + b_hh[row];
        WAF[d] = (_Float16)v;
    }
}

// R14 post-mortem: stream bytes not binding either. R15 = R13 base + LDS-pipe
// diet on PROVEN conflict sites: red/red0 stride 80 (2-way), nhS/ncS -> [c][b][h]
// + packed b128/b64 phase-A writes, m=0 A-frags in registers (not LDS).
#define E1P(BB, V) { \
    V = b1_l[lane] \
      + red[par][1][BB][lane] + red[par][2][BB][lane] + red[par][3][BB][lane] \
      + red[par][4][BB][lane] + red[par][5][BB][lane] + red[par][6][BB][lane] \
      + red[par][7][BB][lane]; }

#define E1F(BB, V) { \
    V += errdotS[BB][lane] \
       + red0[0][BB][lane] + red0[1][BB][lane] + red0[2][BB][lane] + red0[3][BB][lane]; \
    e1S[BB][lane] = fmaxf(V, 0.f); }

__global__ __attribute__((amdgpu_flat_work_group_size(NTHR, NTHR)))
void mmoe_kernel(const float* __restrict__ x, const float* __restrict__ pred0,
                 const float* __restrict__ gate0,
                 const float* __restrict__ W_ih, const float* __restrict__ W_hh,
                 const float* __restrict__ b_ih, const float* __restrict__ b_hh,
                 const float* __restrict__ W_o, const float* __restrict__ b_o,
                 const float* __restrict__ W1, const float* __restrict__ b1,
                 const float* __restrict__ W2, const float* __restrict__ b2,
                 const float* __restrict__ Wg, const float* __restrict__ bg,
                 const float* __restrict__ Wa_ih, const float* __restrict__ Wa_hh,
                 const float* __restrict__ ba_ih, const float* __restrict__ ba_hh,
                 const _Float16* __restrict__ W1F, const _Float16* __restrict__ WAF,
                 float* __restrict__ out)
{
    __shared__ __align__(16) _Float16 ringH[NB * RSTR];      // skewed ring (h rows)
    __shared__ __align__(16) _Float16 ehH[NB][40];           // [eh(16)|x|1|0..] f16
    __shared__ float errS[NB][MEM];
    __shared__ __align__(16) float WaI[2][64 * 20], WaH[2][64 * 20];
    __shared__ float ba_l[2][64];
    __shared__ __align__(16) float W2_l[16 * 68];
    __shared__ float b2_l[16];
    __shared__ __align__(16) float Wg_l[8][16], Wo_l[8][16];
    __shared__ float bg_l[8], bo_l[8];
    __shared__ float Werr_l[MEM * 64];
    __shared__ float b1_l[64];
    __shared__ float xS[NB][S_LEN];
    __shared__ __align__(16) float ecS[NB][HID];
    __shared__ __align__(16) float nhS[NCELL][NB][HID];      // [c][b][h]: 2-way banks
    __shared__ __align__(16) float ncS[NCELL][NB][HID];
    __shared__ float oS[NB][NCELL], predS[NB], gateS[NB][NCELL];
    __shared__ __align__(16) float ahS[2][NB][HID], acS[2][NB][HID];
    __shared__ __align__(16) float e1S[NB][64], aiS[NB][HID];
    __shared__ __align__(16) float glog[NB][8];
    __shared__ __align__(16) float red[2][8][NB][RP];        // stream partials (pad 80)
    __shared__ __align__(16) float red0[4][NB][RP];          // m=0 term (pad 80)
    __shared__ float errdotS[NB][64];
    __shared__ float thS[NB];

    const int tid = threadIdx.x;
    const int b0 = blockIdx.x * NB;
    const int lane = tid & 63, wv = tid >> 6;
    const int quad = lane >> 4, nn = lane & 15, bb4 = nn & 3;

    // ---- one-time staging ----
    for (int i = tid; i < 2048; i += NTHR) {
        int l = i >> 10, r = i & 1023, g = r >> 4, q = r & 15;
        WaI[l][g * 20 + q] = Wa_ih[i]; WaH[l][g * 20 + q] = Wa_hh[i];
    }
    for (int i = tid; i < 128; i += NTHR) { int l = i >> 6, g = i & 63; ba_l[l][g] = ba_ih[i] + ba_hh[i]; }
    for (int i = tid; i < 1024; i += NTHR) { int r = i >> 6, q = i & 63; W2_l[r * 68 + q] = W2[i]; }
    for (int i = tid; i < 1280; i += NTHR) { int m = i >> 6, j = i & 63; Werr_l[i] = W1[j * 2580 + m * 129 + 128]; }
    if (tid < 64) b1_l[tid] = b1[tid];
    if (tid < 16) b2_l[tid] = b2[tid];
    if (tid < 128) { int c = tid >> 4, h = tid & 15; Wg_l[c][h] = Wg[tid]; Wo_l[c][h] = W_o[tid]; }
    if (tid < 8) { bg_l[tid] = bg[tid]; bo_l[tid] = b_o[tid]; }
    for (int i = tid; i < NB * S_LEN; i += NTHR) { int b = i >> 8, s = i & 255; xS[b][s] = x[(b0 + b) * S_LEN + s]; }
    for (int i = tid; i < NB * RSTR; i += NTHR) ringH[i] = (_Float16)0.0f;
    for (int i = tid; i < 2 * 8 * NB * RP; i += NTHR) ((float*)red)[i] = 0.0f;
    if (tid < NB * 40) {
        int n = tid / 40, k = tid % 40;
        float v = 0.f;
        if (k == 16) v = x[(b0 + n) * S_LEN + 0];
        else if (k == 17) v = 1.0f;
        ehH[n][k] = (_Float16)v;
    }
    if (tid < NB * MEM) { int b = tid / MEM, m = tid % MEM; errS[b][m] = 0.5f; }
    if (tid < NB * HID) {
        int b = tid >> 4, h = tid & 15;
        ecS[b][h] = 0.f;
        ahS[0][b][h] = 0.f; ahS[1][b][h] = 0.f;
        acS[0][b][h] = 0.f; acS[1][b][h] = 0.f;
    }
    if (tid < NB) predS[tid] = pred0[b0 + tid];
    if (tid < NB * NCELL) { int b = tid >> 3, c = tid & 7; gateS[b][c] = gate0[(b0 + b) * NCELL + c]; }

    // ---- loop-invariant register A-frags ----
    const v8h* WA = (const v8h*)WAF;
    v8h aI = WA[(wv * 4 + 0) * 64 + lane];
    v8h aF = WA[(wv * 4 + 1) * 64 + lane];
    v8h aG = WA[(wv * 4 + 2) * 64 + lane];
    v8h aO = WA[(wv * 4 + 3) * 64 + lane];
    const v8h* Wb = (const v8h*)W1F;
    const int kcW = wv >> 1, jt0W = (wv & 1) * 2;
    v8h m0A = Wb[(size_t)(kcW * 4 + jt0W) * 64 + lane];      // m=0 A-frags (was LDS)
    v8h m0B = Wb[(size_t)(kcW * 4 + jt0W + 1) * 64 + lane];
    __syncthreads();

    int head = 0;
    #pragma unroll 1
    for (int t = 0; t < S_LEN; ++t) {
        head = (head == 0) ? (MEM - 1) : (head - 1);
        const int par = t & 1, np = par ^ 1;
        float v0, v1, v2, v3;

        // ---- Section 1: phase A via MFMA (wave = cell wv) ----
        {
            v8h bfrag = *(const v8h*)&ehH[bb4][quad * 8];
            v4f z4 = {0.f, 0.f, 0.f, 0.f};
            v4f zi = mfma16(aI, bfrag, z4);
            v4f zf = mfma16(aF, bfrag, z4);
            v4f zg = mfma16(aG, bfrag, z4);
            v4f zo = mfma16(aO, bfrag, z4);
            if (nn < 4) {
                int b = nn, c = wv;
                v4f hv4, cv4; v4h hr;
                #pragma unroll
                for (int r = 0; r < 4; ++r) {
                    int h = quad * 4 + r;
                    float cc = ecS[b][h];
                    float c2 = sigm(zf[r]) * cc + sigm(zi[r]) * tanh_f(zg[r]);
                    float hv = sigm(zo[r]) * tanh_f(c2);
                    hv4[r] = hv; cv4[r] = c2; hr[r] = (_Float16)hv;
                }
                *(v4f*)&nhS[c][b][quad * 4] = hv4;           // packed b128, 2-way banks
                *(v4f*)&ncS[c][b][quad * 4] = cv4;
                *(v4h*)&RING(b, head, c * 16 + quad * 4) = hr;  // packed b64
            }
            if (tid < NB) errS[tid][head] = xS[tid][t] - predS[tid];
        }
        __syncthreads();   // B1

        // ---- Section 2a: m=0 MFMA (register A-frags) + parallel tail-prep ----
        {
            v8h bfrag = *(const v8h*)&RING(bb4, head, kcW * 32 + quad * 8);
            v4f z = {0.f, 0.f, 0.f, 0.f};
            v4f c0 = mfma16(m0A, bfrag, z);
            v4f c1 = mfma16(m0B, bfrag, z);
            if (nn < 4) {
                *(v4f*)&red0[kcW][nn][jt0W * 16 + quad * 4] = c0;
                *(v4f*)&red0[kcW][nn][(jt0W + 1) * 16 + quad * 4] = c1;
            }
            if (wv == 0) {
                E1P(0, v0) E1P(1, v1) E1P(2, v2) E1P(3, v3)
            } else if (wv == 1) {
                if (lane < 32) {
                    int bb = lane >> 3, c = lane & 7;
                    const float4* np_ = (const float4*)&nhS[c][bb][0];
                    const float4* wp = (const float4*)&Wo_l[c][0];
                    float s = bo_l[c];
                    #pragma unroll
                    for (int q4 = 0; q4 < 4; ++q4) s += dot4(np_[q4], wp[q4]);
                    oS[bb][c] = s;
                }
            } else if (wv == 2) {
                if (lane < NB) {
                    float th = 0.f;
                    #pragma unroll
                    for (int m = 0; m < 10; ++m) {
                        int sl = head + m; if (sl >= MEM) sl -= MEM;
                        th += fabsf(errS[lane][sl]);
                    }
                    th *= 0.25f;
                    thS[lane] = fminf(fmaxf(th, 0.f), 1.f);
                }
            } else if (wv >= 3 && wv < 7) {
                int bb = wv - 3;
                float s = 0.f;
                int sl = head;
                #pragma unroll
                for (int m = 0; m < MEM; ++m) {
                    s = fmaf(Werr_l[m * 64 + lane], errS[bb][sl], s);
                    ++sl; if (sl >= MEM) sl = 0;
                }
                errdotS[bb][lane] = s;
            }
        }
        __syncthreads();   // B2

        // ---- Section 2b: stream m=1..19 (waves 1-7, depth-1) || tail (wave 0) ----
        if (wv >= 1) {
            int kt = (wv - 1) * 11;
            int ktEnd = kt + 11; if (ktEnd > 76) ktEnd = 76;
            v4f c0 = {0.f,0.f,0.f,0.f}, c1 = {0.f,0.f,0.f,0.f};
            v4f c2 = {0.f,0.f,0.f,0.f}, c3 = {0.f,0.f,0.f,0.f};
            size_t tb = (size_t)(4 + kt) * 256 + lane;
            v8h pA0 = Wb[tb], pA1 = Wb[tb + 64], pA2 = Wb[tb + 128], pA3 = Wb[tb + 192];
            int m0 = 1 + (kt >> 2), kc0 = kt & 3;
            int s0 = head + m0 - 1; if (s0 >= MEM) s0 -= MEM;
            v8h pB = *(const v8h*)&RING(bb4, s0, kc0 * 32 + quad * 8);
            #pragma unroll 1
            for (; kt < ktEnd; ++kt) {
                v8h A0 = pA0, A1 = pA1, A2 = pA2, A3 = pA3, B = pB;
                int kn = kt + 1;
                if (kn < ktEnd) {
                    size_t tn = (size_t)(4 + kn) * 256 + lane;
                    pA0 = Wb[tn]; pA1 = Wb[tn + 64]; pA2 = Wb[tn + 128]; pA3 = Wb[tn + 192];
                    int mn = 1 + (kn >> 2), kcn = kn & 3;
                    int sn = head + mn - 1; if (sn >= MEM) sn -= MEM;
                    pB = *(const v8h*)&RING(bb4, sn, kcn * 32 + quad * 8);
                }
                c0 = mfma16(A0, B, c0);
                c1 = mfma16(A1, B, c1);
                c2 = mfma16(A2, B, c2);
                c3 = mfma16(A3, B, c3);
            }
            if (nn < 4) {
                *(v4f*)&red[np][wv][nn][ 0 + quad * 4] = c0;
                *(v4f*)&red[np][wv][nn][16 + quad * 4] = c1;
                *(v4f*)&red[np][wv][nn][32 + quad * 4] = c2;
                *(v4f*)&red[np][wv][nn][48 + quad * 4] = c3;
            }
        } else {
            // ---- tail (wave 0) ----
            E1F(0, v0) E1F(1, v1) E1F(2, v2) E1F(3, v3)
            const int j = lane;
            {   // ai: 64 lanes = 4b x 16i
                int bb = j >> 4, i = j & 15;
                const float4* epq = (const float4*)&e1S[bb][0];
                float s = b2_l[i];
                #pragma unroll
                for (int q = 0; q < 16; ++q) s += dot4(*(const float4*)&W2_l[i * 68 + q * 4], epq[q]);
                aiS[bb][i] = fmaxf(s, 0.f);
            }
            #pragma unroll
            for (int l = 0; l < 2; ++l) {   // agent LSTM: 4b x 16h
                int bb = j >> 4, h = j & 15;
                const float4* ip = (l == 0) ? (const float4*)&aiS[bb][0]
                                            : (const float4*)&ahS[0][bb][0];
                const float4* hp = (const float4*)&ahS[l][bb][0];
                float4 i0 = ip[0], i1 = ip[1], i2 = ip[2], i3 = ip[3];
                float4 h0 = hp[0], h1 = hp[1], h2v = hp[2], h3 = hp[3];
                float zg[4];
                #pragma unroll
                for (int gi = 0; gi < 4; ++gi) {
                    int g = gi * 16 + h;
                    const float* wi = &WaI[l][g * 20];
                    const float* wh = &WaH[l][g * 20];
                    float z = ba_l[l][g];
                    z += dot4(i0, *(const float4*)&wi[0]) + dot4(i1, *(const float4*)&wi[4])
                       + dot4(i2, *(const float4*)&wi[8]) + dot4(i3, *(const float4*)&wi[12]);
                    z += dot4(h0, *(const float4*)&wh[0]) + dot4(h1, *(const float4*)&wh[4])
                       + dot4(h2v, *(const float4*)&wh[8]) + dot4(h3, *(const float4*)&wh[12]);
                    zg[gi] = z;
                }
                float c2 = sigm(zg[1]) * acS[l][bb][h] + sigm(zg[0]) * tanh_f(zg[2]);
                acS[l][bb][h] = c2;
                ahS[l][bb][h] = sigm(zg[3]) * tanh_f(c2);
            }
            if (j < 32) {   // gate logits + softmax + theta blend
                int bb = j >> 3, c = j & 7;
                const float4* hp = (const float4*)&ahS[1][bb][0];
                const float4* wg = (const float4*)&Wg_l[c][0];
                float s = bg_l[c];
                #pragma unroll
                for (int q = 0; q < 4; ++q) s += dot4(wg[q], hp[q]);
                glog[bb][c] = s;
                float4 ga = *(const float4*)&glog[bb][0];
                float4 gb = *(const float4*)&glog[bb][4];
                float mx = fmaxf(fmaxf(fmaxf(ga.x, ga.y), fmaxf(ga.z, ga.w)),
                                 fmaxf(fmaxf(gb.x, gb.y), fmaxf(gb.z, gb.w)));
                float sum = __expf(ga.x - mx) + __expf(ga.y - mx) + __expf(ga.z - mx) + __expf(ga.w - mx)
                          + __expf(gb.x - mx) + __expf(gb.y - mx) + __expf(gb.z - mx) + __expf(gb.w - mx);
                float p = __expf(s - mx) / sum;
                float th = thS[bb];
                gateS[bb][c] = p * th + gateS[bb][c] * (1.f - th);
            }
            {   // combine -> ehH + ecS
                int bb = j >> 4, h = j & 15;
                float se = 0.f, sc = 0.f;
                #pragma unroll
                for (int c = 0; c < 8; ++c) {
                    float g = gateS[bb][c];
                    se = fmaf(g, nhS[c][bb][h], se);
                    sc = fmaf(g, ncS[c][bb][h], sc);
                }
                ehH[bb][h] = (_Float16)se;
                ecS[bb][h] = sc;
            }
            if (j < NB) {   // pred + output + next x slot
                float s = 0.f;
                #pragma unroll
                for (int c = 0; c < 8; ++c) s = fmaf(gateS[j][c], oS[j][c], s);
                predS[j] = s;
                out[(b0 + j) * S_LEN + t] = s;
                ehH[j][16] = (_Float16)((t + 1 < S_LEN) ? xS[j][t + 1] : 0.f);
            }
        }
        __syncthreads();   // B3
    }
}

extern "C" void kernel_launch(void* const* d_in, const int* in_sizes, int n_in,
                              void* d_out, int out_size, void* d_ws, size_t ws_size,
                              hipStream_t stream) {
    const float* xp    = (const float*)d_in[0];
    const float* pred0 = (const float*)d_in[1];
    const float* gate0 = (const float*)d_in[2];
    const float* W_ih  = (const float*)d_in[3];
    const float* W_hh  = (const float*)d_in[4];
    const float* b_ih  = (const float*)d_in[5];
    const float* b_hh  = (const float*)d_in[6];
    const float* W_o   = (const float*)d_in[7];
    const float* b_o   = (const float*)d_in[8];
    const float* W1    = (const float*)d_in[9];
    const float* b1    = (const float*)d_in[10];
    const float* W2    = (const float*)d_in[11];
    const float* b2    = (const float*)d_in[12];
    const float* Wg    = (const float*)d_in[13];
    const float* bg    = (const float*)d_in[14];
    const float* Wa_ih = (const float*)d_in[15];
    const float* Wa_hh = (const float*)d_in[16];
    const float* ba_ih = (const float*)d_in[17];
    const float* ba_hh = (const float*)d_in[18];
    _Float16* W1F = (_Float16*)d_ws;                 // 320 KB
    _Float16* WAF = W1F + 163840;                    // +32 KB expert A-frags

    prep_w<<<(163840 + 16384 + 255) / 256, 256, 0, stream>>>(
        W1, W_hh, W_ih, b_ih, b_hh, W1F, WAF);
    mmoe_kernel<<<512 / NB, NTHR, 0, stream>>>(
        xp, pred0, gate0, W_ih, W_hh, b_ih, b_hh, W_o, b_o,
        W1, b1, W2, b2, Wg, bg, Wa_ih, Wa_hh, ba_ih, ba_hh,
        W1F, WAF, (float*)d_out);
}